// Round 5
// baseline (1439.260 us; speedup 1.0000x reference)
//
#include <hip/hip_runtime.h>

#define N_NODES 100000
#define DIM 256
#define KC 16
#define NE 3200000

// ---------------------------------------------------------------------------
// Thread-per-node: logits = X[node]·W^T + b, softmax -> S (f32 in d_out),
// cluster_sizes wave-reduced -> atomics. W reads are wave-uniform -> s_load.
// ---------------------------------------------------------------------------
__global__ __launch_bounds__(256) void k_assign(const float* __restrict__ X,
                                                const float4* __restrict__ W4,
                                                const float* __restrict__ bias,
                                                float* __restrict__ S,
                                                float* __restrict__ cs_g) {
    int node = blockIdx.x * 256 + threadIdx.x;
    float p[KC];
    #pragma unroll
    for (int k = 0; k < KC; k++) p[k] = 0.f;

    if (node < N_NODES) {
        float acc[KC];
        #pragma unroll
        for (int k = 0; k < KC; k++) acc[k] = bias[k];
        const float4* xr = (const float4*)(X + (size_t)node * DIM);
        for (int j4 = 0; j4 < 64; j4++) {
            float4 x = xr[j4];
            #pragma unroll
            for (int k = 0; k < KC; k++) {
                float4 w = W4[k * 64 + j4];   // wave-uniform -> scalar load
                acc[k] += x.x * w.x + x.y * w.y + x.z * w.z + x.w * w.w;
            }
        }
        float m = acc[0];
        #pragma unroll
        for (int k = 1; k < KC; k++) m = fmaxf(m, acc[k]);
        float s = 0.f;
        #pragma unroll
        for (int k = 0; k < KC; k++) { float e = __expf(acc[k] - m); acc[k] = e; s += e; }
        float inv = 1.f / s;
        #pragma unroll
        for (int k = 0; k < KC; k++) p[k] = acc[k] * inv;

        float4* srow = (float4*)(S + (size_t)node * KC);
        srow[0] = make_float4(p[0],  p[1],  p[2],  p[3]);
        srow[1] = make_float4(p[4],  p[5],  p[6],  p[7]);
        srow[2] = make_float4(p[8],  p[9],  p[10], p[11]);
        srow[3] = make_float4(p[12], p[13], p[14], p[15]);
    }

    #pragma unroll
    for (int k = 0; k < KC; k++) {
        float v = p[k];
        #pragma unroll
        for (int off = 32; off >= 1; off >>= 1) v += __shfl_xor(v, off);
        if ((threadIdx.x & 63) == 0) atomicAdd(&cs_g[k], v);
    }
}

// ---------------------------------------------------------------------------
// Per-edge fused: m2 += adj; tr += adj * dot(S[row],S[col]);
// left[k] += adj * S[row][k]   (left = S^T degrees, degrees never stored)
// ---------------------------------------------------------------------------
__global__ __launch_bounds__(256) void k_edges(const int* __restrict__ rows,
                                               const int* __restrict__ cols,
                                               const float* __restrict__ adj,
                                               const float* __restrict__ S,
                                               float* __restrict__ m2_g,
                                               float* __restrict__ tr_g,
                                               float* __restrict__ left_g) {
    float m2l = 0.f, trl = 0.f;
    float lf[KC];
    #pragma unroll
    for (int k = 0; k < KC; k++) lf[k] = 0.f;

    int stride = gridDim.x * blockDim.x;
    for (int e = blockIdx.x * blockDim.x + threadIdx.x; e < NE; e += stride) {
        int r = rows[e], c = cols[e];
        float a = adj[e];
        const float4* sr = (const float4*)(S + (size_t)r * KC);
        const float4* sc = (const float4*)(S + (size_t)c * KC);
        float d = 0.f;
        #pragma unroll
        for (int q = 0; q < 4; q++) {
            float4 sv = sr[q];
            float4 cv = sc[q];
            d += sv.x * cv.x + sv.y * cv.y + sv.z * cv.z + sv.w * cv.w;
            lf[4 * q + 0] += a * sv.x;
            lf[4 * q + 1] += a * sv.y;
            lf[4 * q + 2] += a * sv.z;
            lf[4 * q + 3] += a * sv.w;
        }
        m2l += a;
        trl += a * d;
    }

    #pragma unroll
    for (int off = 32; off >= 1; off >>= 1) {
        m2l += __shfl_xor(m2l, off);
        trl += __shfl_xor(trl, off);
    }
    if ((threadIdx.x & 63) == 0) {
        atomicAdd(m2_g, m2l);
        atomicAdd(tr_g, trl);
    }
    #pragma unroll
    for (int k = 0; k < KC; k++) {
        float v = lf[k];
        #pragma unroll
        for (int off = 32; off >= 1; off >>= 1) v += __shfl_xor(v, off);
        if ((threadIdx.x & 63) == 0) atomicAdd(&left_g[k], v);
    }
}

// ---------------------------------------------------------------------------
// stx[k][d] = sum_i S[i][k] * X[i][d]   (thread owns column d; S via LDS)
// ---------------------------------------------------------------------------
__global__ __launch_bounds__(256) void k_stx(const float* __restrict__ X,
                                             const float* __restrict__ S,
                                             float* __restrict__ stx) {
    __shared__ float s_sh[KC * KC];  // 16 nodes x 16 clusters
    float acc[KC];
    #pragma unroll
    for (int k = 0; k < KC; k++) acc[k] = 0.f;
    const int d = threadIdx.x;
    const int nchunks = N_NODES / 16;
    for (int ch = blockIdx.x; ch < nchunks; ch += gridDim.x) {
        int base = ch * 16;
        __syncthreads();
        s_sh[threadIdx.x] = S[(size_t)base * KC + threadIdx.x];  // 256 floats
        __syncthreads();
        #pragma unroll 4
        for (int i = 0; i < 16; i++) {
            float xv = X[(size_t)(base + i) * DIM + d];
            const float* srow = s_sh + i * KC;
            #pragma unroll
            for (int k = 0; k < KC; k++) acc[k] += srow[k] * xv;  // LDS broadcast
        }
    }
    #pragma unroll
    for (int k = 0; k < KC; k++) atomicAdd(&stx[k * DIM + d], acc[k]);
}

// ---------------------------------------------------------------------------
// epilogue: features_pooled = selu(stx/cs), spectral & collapse losses (f32)
// ---------------------------------------------------------------------------
__global__ __launch_bounds__(256) void k_final(const float* __restrict__ cs,
                                               const float* __restrict__ left,
                                               const float* __restrict__ m2p,
                                               const float* __restrict__ trp,
                                               const float* __restrict__ stx,
                                               float* __restrict__ out) {
    int t = threadIdx.x;
    #pragma unroll
    for (int k = 0; k < KC; k++) {
        float v = stx[k * DIM + t] / cs[k];
        float r = (v > 0.f) ? 1.0507009873554805f * v
                            : 1.7580993408473766f * (__expf(v) - 1.f);
        out[k * DIM + t] = r;
    }
    if (t == 0) {
        float m2 = *m2p;
        float tn = 0.f;
        #pragma unroll
        for (int k = 0; k < KC; k++) tn += left[k] * left[k];
        tn /= m2;
        float spectral = -((*trp) - tn) / m2;
        float ss = 0.f;
        #pragma unroll
        for (int k = 0; k < KC; k++) ss += cs[k] * cs[k];
        float collapse = 0.1f * (sqrtf(ss) / (float)N_NODES * 4.0f - 1.0f);
        out[KC * DIM + (size_t)N_NODES * KC]     = spectral;
        out[KC * DIM + (size_t)N_NODES * KC + 1] = collapse;
    }
}

extern "C" void kernel_launch(void* const* d_in, const int* in_sizes, int n_in,
                              void* d_out, int out_size, void* d_ws, size_t ws_size,
                              hipStream_t stream) {
    (void)out_size; (void)ws_size;

    // Identify inputs by flat element count (all five sizes are distinct;
    // proven equivalent to dict order in round 4).
    const float* X    = nullptr;   // features   [100000,256] f32 -> 25,600,000
    const int*   ei   = nullptr;   // edge_index [2,3200000] i32  ->  6,400,000
    const float* adj  = nullptr;   // adj_vals   [3200000]   f32  ->  3,200,000
    const float* W    = nullptr;   // W          [16,256]    f32  ->      4,096
    const float* bias = nullptr;   // b          [16]        f32  ->         16
    for (int i = 0; i < n_in; i++) {
        switch (in_sizes[i]) {
            case 25600000: X    = (const float*)d_in[i]; break;
            case  6400000: ei   = (const int*)d_in[i];   break;
            case  3200000: adj  = (const float*)d_in[i]; break;
            case     4096: W    = (const float*)d_in[i]; break;
            case       16: bias = (const float*)d_in[i]; break;
        }
    }

    float* out = (float*)d_out;     // f32 outputs, concatenated in return order
    float* S   = out + KC * DIM;    // assignments region [100000,16]
    const int* rows = ei;
    const int* cols = ei + NE;

    // tiny workspace: 64 + 4096 floats = 16.6 KB
    float* ws   = (float*)d_ws;
    float* cs   = ws;          // [16]
    float* left = ws + 16;     // [16]
    float* m2   = ws + 32;     // [1]
    float* tr   = ws + 33;     // [1]
    float* stx  = ws + 64;     // [16*256]
    hipMemsetAsync(d_ws, 0, (64 + KC * DIM) * sizeof(float), stream);

    k_assign<<<391, 256, 0, stream>>>(X, (const float4*)W, bias, S, cs);
    k_edges <<<1024, 256, 0, stream>>>(rows, cols, adj, S, m2, tr, left);
    k_stx   <<<256, 256, 0, stream>>>(X, S, stx);
    k_final <<<1, 256, 0, stream>>>(cs, left, m2, tr, stx, out);
}

// Round 6
// 629.169 us; speedup vs baseline: 2.2876x; 2.2876x over previous
//
#include <hip/hip_runtime.h>

#define N_NODES 100000
#define DIM 256
#define KC 16
#define NE 3200000

__device__ __forceinline__ float bflo(unsigned u) { return __uint_as_float(u << 16); }
__device__ __forceinline__ float bfhi(unsigned u) { return __uint_as_float(u & 0xffff0000u); }
__device__ __forceinline__ unsigned short f2bf(float f) {  // RNE
    unsigned u = __float_as_uint(f);
    return (unsigned short)((u + 0x7fffu + ((u >> 16) & 1u)) >> 16);
}
__device__ __forceinline__ unsigned packbf(float a, float b) {
    return (unsigned)f2bf(a) | ((unsigned)f2bf(b) << 16);
}

// ---------------------------------------------------------------------------
// Thread-per-node: logits = X[node]·W^T + b, softmax -> S f32 (d_out) and
// optionally Sb bf16-packed (ws, 32 B/row) for the edge-gather kernel.
// W reads are wave-uniform -> scalar loads.
// ---------------------------------------------------------------------------
template <bool WRITE_BF16>
__global__ __launch_bounds__(256) void k_assign(const float* __restrict__ X,
                                                const float4* __restrict__ W4,
                                                const float* __restrict__ bias,
                                                float* __restrict__ S,
                                                unsigned* __restrict__ Sb,
                                                float* __restrict__ cs_g) {
    int node = blockIdx.x * 256 + threadIdx.x;
    float p[KC];
    #pragma unroll
    for (int k = 0; k < KC; k++) p[k] = 0.f;

    if (node < N_NODES) {
        float acc[KC];
        #pragma unroll
        for (int k = 0; k < KC; k++) acc[k] = bias[k];
        const float4* xr = (const float4*)(X + (size_t)node * DIM);
        for (int j4 = 0; j4 < 64; j4++) {
            float4 x = xr[j4];
            #pragma unroll
            for (int k = 0; k < KC; k++) {
                float4 w = W4[k * 64 + j4];   // wave-uniform -> s_load
                acc[k] += x.x * w.x + x.y * w.y + x.z * w.z + x.w * w.w;
            }
        }
        float m = acc[0];
        #pragma unroll
        for (int k = 1; k < KC; k++) m = fmaxf(m, acc[k]);
        float s = 0.f;
        #pragma unroll
        for (int k = 0; k < KC; k++) { float e = __expf(acc[k] - m); acc[k] = e; s += e; }
        float inv = 1.f / s;
        #pragma unroll
        for (int k = 0; k < KC; k++) p[k] = acc[k] * inv;

        float4* srow = (float4*)(S + (size_t)node * KC);
        srow[0] = make_float4(p[0],  p[1],  p[2],  p[3]);
        srow[1] = make_float4(p[4],  p[5],  p[6],  p[7]);
        srow[2] = make_float4(p[8],  p[9],  p[10], p[11]);
        srow[3] = make_float4(p[12], p[13], p[14], p[15]);

        if (WRITE_BF16) {
            uint4* brow = (uint4*)(Sb + (size_t)node * 8);
            brow[0] = make_uint4(packbf(p[0], p[1]),  packbf(p[2], p[3]),
                                 packbf(p[4], p[5]),  packbf(p[6], p[7]));
            brow[1] = make_uint4(packbf(p[8], p[9]),  packbf(p[10], p[11]),
                                 packbf(p[12], p[13]), packbf(p[14], p[15]));
        }
    }

    #pragma unroll
    for (int k = 0; k < KC; k++) {
        float v = p[k];
        #pragma unroll
        for (int off = 32; off >= 1; off >>= 1) v += __shfl_xor(v, off);
        if ((threadIdx.x & 63) == 0) atomicAdd(&cs_g[k], v);
    }
}

// ---------------------------------------------------------------------------
// Per-edge fused: m2 += adj; tr += adj*dot(S[row],S[col]); left += adj*S[row].
// BF16 path gathers 32 B rows from L2-resident Sb; block-level reduction.
// ---------------------------------------------------------------------------
template <bool BF16>
__global__ __launch_bounds__(256) void k_edges(const int* __restrict__ rows,
                                               const int* __restrict__ cols,
                                               const float* __restrict__ adj,
                                               const float* __restrict__ S,
                                               const unsigned* __restrict__ Sb,
                                               float* __restrict__ m2_g,
                                               float* __restrict__ tr_g,
                                               float* __restrict__ left_g) {
    float m2l = 0.f, trl = 0.f;
    float lf[KC];
    #pragma unroll
    for (int k = 0; k < KC; k++) lf[k] = 0.f;

    int stride = gridDim.x * blockDim.x;
    for (int e = blockIdx.x * blockDim.x + threadIdx.x; e < NE; e += stride) {
        int r = rows[e], c = cols[e];
        float a = adj[e];
        float sv[KC], cv[KC];
        if (BF16) {
            const uint4* sr = (const uint4*)(Sb + (size_t)r * 8);
            const uint4* sc = (const uint4*)(Sb + (size_t)c * 8);
            uint4 a0 = sr[0], a1 = sr[1];
            uint4 b0 = sc[0], b1 = sc[1];
            sv[0]=bflo(a0.x); sv[1]=bfhi(a0.x); sv[2]=bflo(a0.y);  sv[3]=bfhi(a0.y);
            sv[4]=bflo(a0.z); sv[5]=bfhi(a0.z); sv[6]=bflo(a0.w);  sv[7]=bfhi(a0.w);
            sv[8]=bflo(a1.x); sv[9]=bfhi(a1.x); sv[10]=bflo(a1.y); sv[11]=bfhi(a1.y);
            sv[12]=bflo(a1.z);sv[13]=bfhi(a1.z);sv[14]=bflo(a1.w); sv[15]=bfhi(a1.w);
            cv[0]=bflo(b0.x); cv[1]=bfhi(b0.x); cv[2]=bflo(b0.y);  cv[3]=bfhi(b0.y);
            cv[4]=bflo(b0.z); cv[5]=bfhi(b0.z); cv[6]=bflo(b0.w);  cv[7]=bfhi(b0.w);
            cv[8]=bflo(b1.x); cv[9]=bfhi(b1.x); cv[10]=bflo(b1.y); cv[11]=bfhi(b1.y);
            cv[12]=bflo(b1.z);cv[13]=bfhi(b1.z);cv[14]=bflo(b1.w); cv[15]=bfhi(b1.w);
        } else {
            const float4* sr = (const float4*)(S + (size_t)r * KC);
            const float4* sc = (const float4*)(S + (size_t)c * KC);
            #pragma unroll
            for (int q = 0; q < 4; q++) {
                float4 s4 = sr[q], c4 = sc[q];
                sv[4*q]=s4.x; sv[4*q+1]=s4.y; sv[4*q+2]=s4.z; sv[4*q+3]=s4.w;
                cv[4*q]=c4.x; cv[4*q+1]=c4.y; cv[4*q+2]=c4.z; cv[4*q+3]=c4.w;
            }
        }
        float d = 0.f;
        #pragma unroll
        for (int k = 0; k < KC; k++) {
            d += sv[k] * cv[k];
            lf[k] += a * sv[k];
        }
        m2l += a;
        trl += a * d;
    }

    // wave reduce, then block reduce via LDS, then 18 atomics per block
    #pragma unroll
    for (int off = 32; off >= 1; off >>= 1) {
        m2l += __shfl_xor(m2l, off);
        trl += __shfl_xor(trl, off);
    }
    #pragma unroll
    for (int k = 0; k < KC; k++) {
        float v = lf[k];
        #pragma unroll
        for (int off = 32; off >= 1; off >>= 1) v += __shfl_xor(v, off);
        lf[k] = v;
    }
    __shared__ float red[4][18];
    int w = threadIdx.x >> 6;
    if ((threadIdx.x & 63) == 0) {
        red[w][0] = m2l; red[w][1] = trl;
        #pragma unroll
        for (int k = 0; k < KC; k++) red[w][2 + k] = lf[k];
    }
    __syncthreads();
    int t = threadIdx.x;
    if (t < 18) {
        float v = red[0][t] + red[1][t] + red[2][t] + red[3][t];
        float* dst = (t == 0) ? m2_g : (t == 1) ? tr_g : &left_g[t - 2];
        atomicAdd(dst, v);
    }
}

// ---------------------------------------------------------------------------
// stx[k][d] = sum_i S[i][k] * X[i][d]   (thread owns column d; S via LDS)
// ---------------------------------------------------------------------------
__global__ __launch_bounds__(256) void k_stx(const float* __restrict__ X,
                                             const float* __restrict__ S,
                                             float* __restrict__ stx) {
    __shared__ float s_sh[KC * KC];  // 16 nodes x 16 clusters
    float acc[KC];
    #pragma unroll
    for (int k = 0; k < KC; k++) acc[k] = 0.f;
    const int d = threadIdx.x;
    const int nchunks = N_NODES / 16;
    for (int ch = blockIdx.x; ch < nchunks; ch += gridDim.x) {
        int base = ch * 16;
        __syncthreads();
        s_sh[threadIdx.x] = S[(size_t)base * KC + threadIdx.x];  // 256 floats
        __syncthreads();
        #pragma unroll 4
        for (int i = 0; i < 16; i++) {
            float xv = X[(size_t)(base + i) * DIM + d];
            const float* srow = s_sh + i * KC;
            #pragma unroll
            for (int k = 0; k < KC; k++) acc[k] += srow[k] * xv;  // LDS broadcast
        }
    }
    #pragma unroll
    for (int k = 0; k < KC; k++) atomicAdd(&stx[k * DIM + d], acc[k]);
}

// ---------------------------------------------------------------------------
// epilogue: features_pooled = selu(stx/cs), spectral & collapse losses (f32)
// ---------------------------------------------------------------------------
__global__ __launch_bounds__(256) void k_final(const float* __restrict__ cs,
                                               const float* __restrict__ left,
                                               const float* __restrict__ m2p,
                                               const float* __restrict__ trp,
                                               const float* __restrict__ stx,
                                               float* __restrict__ out) {
    int t = threadIdx.x;
    #pragma unroll
    for (int k = 0; k < KC; k++) {
        float v = stx[k * DIM + t] / cs[k];
        float r = (v > 0.f) ? 1.0507009873554805f * v
                            : 1.7580993408473766f * (__expf(v) - 1.f);
        out[k * DIM + t] = r;
    }
    if (t == 0) {
        float m2 = *m2p;
        float tn = 0.f;
        #pragma unroll
        for (int k = 0; k < KC; k++) tn += left[k] * left[k];
        tn /= m2;
        float spectral = -((*trp) - tn) / m2;
        float ss = 0.f;
        #pragma unroll
        for (int k = 0; k < KC; k++) ss += cs[k] * cs[k];
        float collapse = 0.1f * (sqrtf(ss) / (float)N_NODES * 4.0f - 1.0f);
        out[KC * DIM + (size_t)N_NODES * KC]     = spectral;
        out[KC * DIM + (size_t)N_NODES * KC + 1] = collapse;
    }
}

extern "C" void kernel_launch(void* const* d_in, const int* in_sizes, int n_in,
                              void* d_out, int out_size, void* d_ws, size_t ws_size,
                              hipStream_t stream) {
    (void)out_size;

    const float* X    = nullptr;
    const int*   ei   = nullptr;
    const float* adj  = nullptr;
    const float* W    = nullptr;
    const float* bias = nullptr;
    for (int i = 0; i < n_in; i++) {
        switch (in_sizes[i]) {
            case 25600000: X    = (const float*)d_in[i]; break;
            case  6400000: ei   = (const int*)d_in[i];   break;
            case  3200000: adj  = (const float*)d_in[i]; break;
            case     4096: W    = (const float*)d_in[i]; break;
            case       16: bias = (const float*)d_in[i]; break;
        }
    }

    float* out = (float*)d_out;
    float* S   = out + KC * DIM;    // assignments [100000,16] f32
    const int* rows = ei;
    const int* cols = ei + NE;

    // ws layout: cs[16], left[16], m2, tr, pad -> stx[4096] -> Sb[100000*8 u32]
    float* ws   = (float*)d_ws;
    float* cs   = ws;
    float* left = ws + 16;
    float* m2   = ws + 32;
    float* tr   = ws + 33;
    float* stx  = ws + 64;
    unsigned* Sb = (unsigned*)(ws + 64 + KC * DIM);
    const size_t need = (64 + KC * DIM) * sizeof(float) + (size_t)N_NODES * 32;
    const bool use_bf16 = (ws_size >= need);   // fixed per process -> graph-safe

    hipMemsetAsync(d_ws, 0, (64 + KC * DIM) * sizeof(float), stream);

    if (use_bf16) {
        k_assign<true><<<391, 256, 0, stream>>>(X, (const float4*)W, bias, S, Sb, cs);
        k_edges<true><<<2048, 256, 0, stream>>>(rows, cols, adj, S, Sb, m2, tr, left);
    } else {
        k_assign<false><<<391, 256, 0, stream>>>(X, (const float4*)W, bias, S, Sb, cs);
        k_edges<false><<<2048, 256, 0, stream>>>(rows, cols, adj, S, Sb, m2, tr, left);
    }
    k_stx  <<<1250, 256, 0, stream>>>(X, S, stx);
    k_final<<<1, 256, 0, stream>>>(cs, left, m2, tr, stx, out);
}

// Round 7
// 317.736 us; speedup vs baseline: 4.5297x; 1.9802x over previous
//
#include <hip/hip_runtime.h>

#define N_NODES 100000
#define DIM 256
#define KC 16
#define NE 3200000

__device__ __forceinline__ float bflo(unsigned u) { return __uint_as_float(u << 16); }
__device__ __forceinline__ float bfhi(unsigned u) { return __uint_as_float(u & 0xffff0000u); }
__device__ __forceinline__ unsigned short f2bf(float f) {  // RNE
    unsigned u = __float_as_uint(f);
    return (unsigned short)((u + 0x7fffu + ((u >> 16) & 1u)) >> 16);
}
__device__ __forceinline__ unsigned packbf(float a, float b) {
    return (unsigned)f2bf(a) | ((unsigned)f2bf(b) << 16);
}

// ---------------------------------------------------------------------------
// 4 threads per node (quarter-row each). W staged in LDS with q-stride 257
// (disjoint bank groups per quarter -> conflict-free broadcast ds_read_b128).
// Softmax -> S f32 (d_out) + Sb bf16 (ws). cs block-reduced -> 16 atomics/blk.
// ---------------------------------------------------------------------------
template <bool WRITE_BF16>
__global__ __launch_bounds__(256) void k_assign(const float* __restrict__ X,
                                                const float4* __restrict__ W4,
                                                const float* __restrict__ bias,
                                                float* __restrict__ S,
                                                unsigned* __restrict__ Sb,
                                                float* __restrict__ cs_g) {
    __shared__ float4 Wl[4 * 257];          // Wl[q*257 + k*16 + j4]
    __shared__ float csred[4][KC];
    for (int t = threadIdx.x; t < 1024; t += 256) {
        int k = t >> 6, q = (t >> 4) & 3, j4 = t & 15;
        Wl[q * 257 + k * 16 + j4] = W4[t];  // W4[k*64 + q*16 + j4]
    }
    __syncthreads();

    const int gid  = blockIdx.x * 256 + threadIdx.x;
    const int node = gid >> 2;
    const int q    = gid & 3;
    const bool valid = (node < N_NODES);

    float acc[KC];
    #pragma unroll
    for (int k = 0; k < KC; k++) acc[k] = 0.f;

    if (valid) {
        const float4* xr = (const float4*)(X + (size_t)node * DIM) + q * 16;
        const float4* wq = Wl + q * 257;
        #pragma unroll 4
        for (int j4 = 0; j4 < 16; j4++) {
            float4 x = xr[j4];
            #pragma unroll
            for (int k = 0; k < KC; k++) {
                float4 w = wq[k * 16 + j4];   // broadcast within quarter
                acc[k] += x.x * w.x + x.y * w.y + x.z * w.z + x.w * w.w;
            }
        }
    }
    // reduce quarters (lanes xor 1, xor 2 share the node)
    #pragma unroll
    for (int k = 0; k < KC; k++) {
        acc[k] += __shfl_xor(acc[k], 1);
        acc[k] += __shfl_xor(acc[k], 2);
        acc[k] += bias[k];
    }
    // softmax (all 4 lanes redundantly)
    float m = acc[0];
    #pragma unroll
    for (int k = 1; k < KC; k++) m = fmaxf(m, acc[k]);
    float s = 0.f;
    float p[KC];
    #pragma unroll
    for (int k = 0; k < KC; k++) { float e = __expf(acc[k] - m); p[k] = e; s += e; }
    float inv = valid ? (1.f / s) : 0.f;    // invalid nodes contribute 0
    #pragma unroll
    for (int k = 0; k < KC; k++) p[k] *= inv;

    if (valid) {
        ((float4*)(S + (size_t)node * KC))[q] =
            make_float4(p[4 * q], p[4 * q + 1], p[4 * q + 2], p[4 * q + 3]);
        if (WRITE_BF16 && q < 2) {
            ((uint4*)(Sb + (size_t)node * 8))[q] =
                make_uint4(packbf(p[8 * q + 0], p[8 * q + 1]),
                           packbf(p[8 * q + 2], p[8 * q + 3]),
                           packbf(p[8 * q + 4], p[8 * q + 5]),
                           packbf(p[8 * q + 6], p[8 * q + 7]));
        }
    }

    // cluster sizes: q==0 lanes contribute, wave reduce, block reduce, atomics
    const int w = threadIdx.x >> 6;
    #pragma unroll
    for (int k = 0; k < KC; k++) {
        float v = (q == 0) ? p[k] : 0.f;
        #pragma unroll
        for (int off = 32; off >= 1; off >>= 1) v += __shfl_xor(v, off);
        if ((threadIdx.x & 63) == 0) csred[w][k] = v;
    }
    __syncthreads();
    if (threadIdx.x < KC) {
        int t = threadIdx.x;
        atomicAdd(&cs_g[t], csred[0][t] + csred[1][t] + csred[2][t] + csred[3][t]);
    }
}

// ---------------------------------------------------------------------------
// Per-edge fused: m2 += adj; tr += adj*dot(S[row],S[col]); left += adj*S[row].
// BF16 path gathers 32 B rows from L2-resident Sb; block-level reduction.
// ---------------------------------------------------------------------------
template <bool BF16>
__global__ __launch_bounds__(256) void k_edges(const int* __restrict__ rows,
                                               const int* __restrict__ cols,
                                               const float* __restrict__ adj,
                                               const float* __restrict__ S,
                                               const unsigned* __restrict__ Sb,
                                               float* __restrict__ m2_g,
                                               float* __restrict__ tr_g,
                                               float* __restrict__ left_g) {
    float m2l = 0.f, trl = 0.f;
    float lf[KC];
    #pragma unroll
    for (int k = 0; k < KC; k++) lf[k] = 0.f;

    int stride = gridDim.x * blockDim.x;
    for (int e = blockIdx.x * blockDim.x + threadIdx.x; e < NE; e += stride) {
        int r = rows[e], c = cols[e];
        float a = adj[e];
        float sv[KC], cv[KC];
        if (BF16) {
            const uint4* sr = (const uint4*)(Sb + (size_t)r * 8);
            const uint4* sc = (const uint4*)(Sb + (size_t)c * 8);
            uint4 a0 = sr[0], a1 = sr[1];
            uint4 b0 = sc[0], b1 = sc[1];
            sv[0]=bflo(a0.x); sv[1]=bfhi(a0.x); sv[2]=bflo(a0.y);  sv[3]=bfhi(a0.y);
            sv[4]=bflo(a0.z); sv[5]=bfhi(a0.z); sv[6]=bflo(a0.w);  sv[7]=bfhi(a0.w);
            sv[8]=bflo(a1.x); sv[9]=bfhi(a1.x); sv[10]=bflo(a1.y); sv[11]=bfhi(a1.y);
            sv[12]=bflo(a1.z);sv[13]=bfhi(a1.z);sv[14]=bflo(a1.w); sv[15]=bfhi(a1.w);
            cv[0]=bflo(b0.x); cv[1]=bfhi(b0.x); cv[2]=bflo(b0.y);  cv[3]=bfhi(b0.y);
            cv[4]=bflo(b0.z); cv[5]=bfhi(b0.z); cv[6]=bflo(b0.w);  cv[7]=bfhi(b0.w);
            cv[8]=bflo(b1.x); cv[9]=bfhi(b1.x); cv[10]=bflo(b1.y); cv[11]=bfhi(b1.y);
            cv[12]=bflo(b1.z);cv[13]=bfhi(b1.z);cv[14]=bflo(b1.w); cv[15]=bfhi(b1.w);
        } else {
            const float4* sr = (const float4*)(S + (size_t)r * KC);
            const float4* sc = (const float4*)(S + (size_t)c * KC);
            #pragma unroll
            for (int qq = 0; qq < 4; qq++) {
                float4 s4 = sr[qq], c4 = sc[qq];
                sv[4*qq]=s4.x; sv[4*qq+1]=s4.y; sv[4*qq+2]=s4.z; sv[4*qq+3]=s4.w;
                cv[4*qq]=c4.x; cv[4*qq+1]=c4.y; cv[4*qq+2]=c4.z; cv[4*qq+3]=c4.w;
            }
        }
        float d = 0.f;
        #pragma unroll
        for (int k = 0; k < KC; k++) {
            d += sv[k] * cv[k];
            lf[k] += a * sv[k];
        }
        m2l += a;
        trl += a * d;
    }

    #pragma unroll
    for (int off = 32; off >= 1; off >>= 1) {
        m2l += __shfl_xor(m2l, off);
        trl += __shfl_xor(trl, off);
    }
    #pragma unroll
    for (int k = 0; k < KC; k++) {
        float v = lf[k];
        #pragma unroll
        for (int off = 32; off >= 1; off >>= 1) v += __shfl_xor(v, off);
        lf[k] = v;
    }
    __shared__ float red[4][18];
    int w = threadIdx.x >> 6;
    if ((threadIdx.x & 63) == 0) {
        red[w][0] = m2l; red[w][1] = trl;
        #pragma unroll
        for (int k = 0; k < KC; k++) red[w][2 + k] = lf[k];
    }
    __syncthreads();
    int t = threadIdx.x;
    if (t < 18) {
        float v = red[0][t] + red[1][t] + red[2][t] + red[3][t];
        float* dst = (t == 0) ? m2_g : (t == 1) ? tr_g : &left_g[t - 2];
        atomicAdd(dst, v);
    }
}

// ---------------------------------------------------------------------------
// stx[k][d] = sum_i S[i][k] * X[i][d]   (thread owns column d; S via LDS)
// ---------------------------------------------------------------------------
__global__ __launch_bounds__(256) void k_stx(const float* __restrict__ X,
                                             const float* __restrict__ S,
                                             float* __restrict__ stx) {
    __shared__ float s_sh[KC * KC];
    float acc[KC];
    #pragma unroll
    for (int k = 0; k < KC; k++) acc[k] = 0.f;
    const int d = threadIdx.x;
    const int nchunks = N_NODES / 16;
    for (int ch = blockIdx.x; ch < nchunks; ch += gridDim.x) {
        int base = ch * 16;
        __syncthreads();
        s_sh[threadIdx.x] = S[(size_t)base * KC + threadIdx.x];
        __syncthreads();
        #pragma unroll 4
        for (int i = 0; i < 16; i++) {
            float xv = X[(size_t)(base + i) * DIM + d];
            const float* srow = s_sh + i * KC;
            #pragma unroll
            for (int k = 0; k < KC; k++) acc[k] += srow[k] * xv;
        }
    }
    #pragma unroll
    for (int k = 0; k < KC; k++) atomicAdd(&stx[k * DIM + d], acc[k]);
}

// ---------------------------------------------------------------------------
// epilogue: features_pooled = selu(stx/cs), spectral & collapse losses (f32)
// ---------------------------------------------------------------------------
__global__ __launch_bounds__(256) void k_final(const float* __restrict__ cs,
                                               const float* __restrict__ left,
                                               const float* __restrict__ m2p,
                                               const float* __restrict__ trp,
                                               const float* __restrict__ stx,
                                               float* __restrict__ out) {
    int t = threadIdx.x;
    #pragma unroll
    for (int k = 0; k < KC; k++) {
        float v = stx[k * DIM + t] / cs[k];
        float r = (v > 0.f) ? 1.0507009873554805f * v
                            : 1.7580993408473766f * (__expf(v) - 1.f);
        out[k * DIM + t] = r;
    }
    if (t == 0) {
        float m2 = *m2p;
        float tn = 0.f;
        #pragma unroll
        for (int k = 0; k < KC; k++) tn += left[k] * left[k];
        tn /= m2;
        float spectral = -((*trp) - tn) / m2;
        float ss = 0.f;
        #pragma unroll
        for (int k = 0; k < KC; k++) ss += cs[k] * cs[k];
        float collapse = 0.1f * (sqrtf(ss) / (float)N_NODES * 4.0f - 1.0f);
        out[KC * DIM + (size_t)N_NODES * KC]     = spectral;
        out[KC * DIM + (size_t)N_NODES * KC + 1] = collapse;
    }
}

extern "C" void kernel_launch(void* const* d_in, const int* in_sizes, int n_in,
                              void* d_out, int out_size, void* d_ws, size_t ws_size,
                              hipStream_t stream) {
    (void)out_size;

    const float* X    = nullptr;
    const int*   ei   = nullptr;
    const float* adj  = nullptr;
    const float* W    = nullptr;
    const float* bias = nullptr;
    for (int i = 0; i < n_in; i++) {
        switch (in_sizes[i]) {
            case 25600000: X    = (const float*)d_in[i]; break;
            case  6400000: ei   = (const int*)d_in[i];   break;
            case  3200000: adj  = (const float*)d_in[i]; break;
            case     4096: W    = (const float*)d_in[i]; break;
            case       16: bias = (const float*)d_in[i]; break;
        }
    }

    float* out = (float*)d_out;
    float* S   = out + KC * DIM;    // assignments [100000,16] f32
    const int* rows = ei;
    const int* cols = ei + NE;

    float* ws   = (float*)d_ws;
    float* cs   = ws;
    float* left = ws + 16;
    float* m2   = ws + 32;
    float* tr   = ws + 33;
    float* stx  = ws + 64;
    unsigned* Sb = (unsigned*)(ws + 64 + KC * DIM);
    const size_t need = (64 + KC * DIM) * sizeof(float) + (size_t)N_NODES * 32;
    const bool use_bf16 = (ws_size >= need);   // fixed per process -> graph-safe

    hipMemsetAsync(d_ws, 0, (64 + KC * DIM) * sizeof(float), stream);

    const int agrid = (N_NODES * 4 + 255) / 256;   // 1563
    if (use_bf16) {
        k_assign<true><<<agrid, 256, 0, stream>>>(X, (const float4*)W, bias, S, Sb, cs);
        k_edges<true><<<2048, 256, 0, stream>>>(rows, cols, adj, S, Sb, m2, tr, left);
    } else {
        k_assign<false><<<agrid, 256, 0, stream>>>(X, (const float4*)W, bias, S, Sb, cs);
        k_edges<false><<<2048, 256, 0, stream>>>(rows, cols, adj, S, Sb, m2, tr, left);
    }
    k_stx  <<<1250, 256, 0, stream>>>(X, S, stx);
    k_final<<<1, 256, 0, stream>>>(cs, left, m2, tr, stx, out);
}